// Round 1
// baseline (137.136 us; speedup 1.0000x reference)
//
#include <hip/hip_runtime.h>

// Chamfer distance: B=4, S=4, N=M=4096, D=3, fp32 in/out.
// out[s*B + b] = mean_n min_m d2(n,m) + mean_m min_n d2(n,m)
//
// Inner-loop trick: argmin_m (x2 + y2 - 2xy) = argmin_m (y2/2 - x.y), so the
// per-pair cost is 3 fma + 1 min (y2/2 precomputed at staging). Final
// distance recovered as max(x2 + 2*tmin, 0); clamp commutes with min.

constexpr int B = 4, S = 4, NPTS = 4096;
constexpr int THREADS = 256;
constexpr int CHUNK = 2048;              // 2048 * 16B = 32 KB LDS per stage
constexpr int QTILES = NPTS / THREADS;   // 16 query tiles per (pair, dir)

__global__ __launch_bounds__(THREADS, 2)
void chamfer_kernel(const float* __restrict__ out_pts,
                    const float* __restrict__ tgt_pts,
                    float* __restrict__ out) {
  const int t     = threadIdx.x;
  const int qtile = blockIdx.x;   // 0..15
  const int pair  = blockIdx.y;   // 0..15, pair = b*S + s ([B,S,...] row-major)
  const int dir   = blockIdx.z;   // 0: out->tgt (dist1), 1: tgt->out (dist2)

  const float* qbase = (dir == 0 ? out_pts : tgt_pts) + (size_t)pair * NPTS * 3;
  const float* rbase = (dir == 0 ? tgt_pts : out_pts) + (size_t)pair * NPTS * 3;

  __shared__ float4 sref[CHUNK];   // (rx, ry, rz, 0.5*|r|^2)

  // Per-thread query point, held in registers.
  const int q = qtile * THREADS + t;
  const float qx = qbase[q * 3 + 0];
  const float qy = qbase[q * 3 + 1];
  const float qz = qbase[q * 3 + 2];

  // 8 independent min chains -> enough ILP to hide fma latency at 2 waves/SIMD.
  float mm[8];
  #pragma unroll
  for (int u = 0; u < 8; ++u) mm[u] = 3.0e38f;

  for (int c0 = 0; c0 < NPTS; c0 += CHUNK) {
    if (c0) __syncthreads();       // previous chunk fully consumed
    // Stage CHUNK ref points into LDS with y2h precomputed.
    for (int i = t; i < CHUNK; i += THREADS) {
      const float* p = rbase + (size_t)(c0 + i) * 3;
      float rx = p[0], ry = p[1], rz = p[2];
      float y2h = 0.5f * (rx * rx + ry * ry + rz * rz);
      sref[i] = make_float4(rx, ry, rz, y2h);
    }
    __syncthreads();

    // Hot loop: all lanes read the same LDS address (broadcast, conflict-free).
    for (int k = 0; k < CHUNK; k += 8) {
      #pragma unroll
      for (int u = 0; u < 8; ++u) {
        float4 r = sref[k + u];
        float a = fmaf(-qx, r.x, r.w);   // y2h - qx*rx
        a = fmaf(-qy, r.y, a);
        a = fmaf(-qz, r.z, a);
        mm[u] = fminf(mm[u], a);
      }
    }
  }

  float tmin = fminf(fminf(fminf(mm[0], mm[1]), fminf(mm[2], mm[3])),
                     fminf(fminf(mm[4], mm[5]), fminf(mm[6], mm[7])));
  float x2 = qx * qx + qy * qy + qz * qz;
  float d  = fmaxf(fmaf(2.0f, tmin, x2), 0.0f);   // min squared distance

  // Wave64 butterfly sum.
  #pragma unroll
  for (int off = 1; off < 64; off <<= 1) d += __shfl_xor(d, off, 64);

  __syncthreads();                       // done reading sref; reuse as scratch
  float* red = reinterpret_cast<float*>(sref);
  if ((t & 63) == 0) red[t >> 6] = d;
  __syncthreads();
  if (t == 0) {
    float ssum = red[0] + red[1] + red[2] + red[3];
    int b = pair >> 2, s = pair & 3;     // pair = b*S + s, S = 4
    atomicAdd(&out[s * B + b], ssum * (1.0f / NPTS));
  }
}

extern "C" void kernel_launch(void* const* d_in, const int* in_sizes, int n_in,
                              void* d_out, int out_size, void* d_ws, size_t ws_size,
                              hipStream_t stream) {
  const float* out_pts = (const float*)d_in[0];
  const float* tgt_pts = (const float*)d_in[1];
  // d_in[2] = n_samples (4096), fixed by problem shape.
  float* out = (float*)d_out;

  hipMemsetAsync(out, 0, out_size * sizeof(float), stream);  // d_out re-poisoned each call
  dim3 grid(QTILES, B * S, 2);
  chamfer_kernel<<<grid, THREADS, 0, stream>>>(out_pts, tgt_pts, out);
}